// Round 6
// baseline (675.706 us; speedup 1.0000x reference)
//
#include <hip/hip_runtime.h>

#define D_IN 64
#define D_H 128
#define L_STEPS 16
#define ROWS_PER_BLOCK 32
#define THREADS 256

// ---------------------------------------------------------------------------
// Bit-exact emulation of the numpy float32 reference:
//   h = x @ W_syn + b_syn        (sgemm: per-element sequential FMA chain, k asc)
//   I = h @ W_in  + b_in         (same)
//   16x: v = (0.9f*v + I) - s ;  s = (v >= 1.0f)   (separate f32 roundings)
// All arithmetic via explicit __f*_rn intrinsics so -ffp-contract=fast cannot
// change rounding. Outputs f32: spikes [16,B,128] then v_final [B,128].
// Each block: 32 rows. 256 threads.
// ---------------------------------------------------------------------------
__global__ __launch_bounds__(THREADS) void snn_main(
        const float* __restrict__ x,
        const float* __restrict__ W_syn,
        const float* __restrict__ b_syn,
        const float* __restrict__ W_in,
        const float* __restrict__ b_in,
        float* __restrict__ out,
        int B) {
    __shared__ float xs[ROWS_PER_BLOCK][D_IN];    // 8 KB
    __shared__ float hs[ROWS_PER_BLOCK][D_H];     // 16 KB

    const int tid = threadIdx.x;
    const long long row0 = (long long)blockIdx.x * ROWS_PER_BLOCK;

    // ---- cooperative x block load (2048 floats = 512 float4) ----
    {
        const float4* src = (const float4*)(x + row0 * D_IN);
        float4* dst = (float4*)&xs[0][0];
        dst[tid]       = src[tid];
        dst[tid + 256] = src[tid + 256];
    }
    __syncthreads();

    // ---- stage 1: h[r][j], sequential FMA chain over i = 0..63 ----
    {
        const int j = tid & 127;          // hidden col; wave reads 64 consecutive
        const int rbase = tid >> 7;       // 0 or 1
        float wreg[D_IN];
#pragma unroll
        for (int i = 0; i < D_IN; ++i) wreg[i] = W_syn[i * D_H + j];
        const float bs = b_syn[j];
#pragma unroll
        for (int ii = 0; ii < 16; ++ii) {
            const int r = rbase + 2 * ii;
            const float4* xr = (const float4*)&xs[r][0];
            float acc = 0.0f;
#pragma unroll
            for (int i4 = 0; i4 < 16; ++i4) {          // i ascending, one chain
                float4 xv = xr[i4];
                acc = __fmaf_rn(xv.x, wreg[4 * i4 + 0], acc);
                acc = __fmaf_rn(xv.y, wreg[4 * i4 + 1], acc);
                acc = __fmaf_rn(xv.z, wreg[4 * i4 + 2], acc);
                acc = __fmaf_rn(xv.w, wreg[4 * i4 + 3], acc);
            }
            hs[r][j] = __fadd_rn(acc, bs);             // numpy's separate +b_syn
        }
    }
    __syncthreads();

    // ---- stage 2: I[r][n], sequential FMA chain over j = 0..127 ----
    const int h0 = (tid & 31) * 4;        // hidden quad
    const int rg = (tid >> 5) * 4;        // row group of 4

    float acc[4][4];
#pragma unroll
    for (int rr = 0; rr < 4; ++rr)
#pragma unroll
        for (int q = 0; q < 4; ++q) acc[rr][q] = 0.0f;

#pragma unroll 8
    for (int j4 = 0; j4 < 32; ++j4) {
        float hrow[4][4];
#pragma unroll
        for (int rr = 0; rr < 4; ++rr) {
            float4 h4 = *(const float4*)&hs[rg + rr][4 * j4];
            hrow[rr][0] = h4.x; hrow[rr][1] = h4.y;
            hrow[rr][2] = h4.z; hrow[rr][3] = h4.w;
        }
#pragma unroll
        for (int q4 = 0; q4 < 4; ++q4) {               // j = 4*j4+q4 ascending
            const int j = 4 * j4 + q4;
            float4 w = *(const float4*)&W_in[j * D_H + h0];
#pragma unroll
            for (int rr = 0; rr < 4; ++rr) {
                const float hv = hrow[rr][q4];
                acc[rr][0] = __fmaf_rn(hv, w.x, acc[rr][0]);
                acc[rr][1] = __fmaf_rn(hv, w.y, acc[rr][1]);
                acc[rr][2] = __fmaf_rn(hv, w.z, acc[rr][2]);
                acc[rr][3] = __fmaf_rn(hv, w.w, acc[rr][3]);
            }
        }
    }

    const float4 bi = *(const float4*)&b_in[h0];
    float Iv[4][4];
#pragma unroll
    for (int rr = 0; rr < 4; ++rr) {
        Iv[rr][0] = __fadd_rn(acc[rr][0], bi.x);       // numpy's separate +b_in
        Iv[rr][1] = __fadd_rn(acc[rr][1], bi.y);
        Iv[rr][2] = __fadd_rn(acc[rr][2], bi.z);
        Iv[rr][3] = __fadd_rn(acc[rr][3], bi.w);
    }

    // ---- recurrence: uncontracted f32, numpy op order ----
    const size_t BH = (size_t)B * D_H;
    float* __restrict__ vout = out + (size_t)L_STEPS * BH;

#pragma unroll
    for (int rr = 0; rr < 4; ++rr) {
        const size_t base = (size_t)(row0 + rg + rr) * D_H + (size_t)h0;
        float v0 = 0.f, v1 = 0.f, v2 = 0.f, v3 = 0.f;
        float s0 = 0.f, s1 = 0.f, s2 = 0.f, s3 = 0.f;
        const float I0 = Iv[rr][0], I1 = Iv[rr][1], I2 = Iv[rr][2], I3 = Iv[rr][3];
#pragma unroll
        for (int t = 0; t < L_STEPS; ++t) {
            v0 = __fsub_rn(__fadd_rn(__fmul_rn(0.9f, v0), I0), s0);
            v1 = __fsub_rn(__fadd_rn(__fmul_rn(0.9f, v1), I1), s1);
            v2 = __fsub_rn(__fadd_rn(__fmul_rn(0.9f, v2), I2), s2);
            v3 = __fsub_rn(__fadd_rn(__fmul_rn(0.9f, v3), I3), s3);
            s0 = (v0 >= 1.0f) ? 1.0f : 0.0f;
            s1 = (v1 >= 1.0f) ? 1.0f : 0.0f;
            s2 = (v2 >= 1.0f) ? 1.0f : 0.0f;
            s3 = (v3 >= 1.0f) ? 1.0f : 0.0f;
            float4 s4 = make_float4(s0, s1, s2, s3);
            *(float4*)(out + (size_t)t * BH + base) = s4;
        }
        float4 v4 = make_float4(v0, v1, v2, v3);
        *(float4*)(vout + base) = v4;
    }
}

extern "C" void kernel_launch(void* const* d_in, const int* in_sizes, int n_in,
                              void* d_out, int out_size, void* d_ws, size_t ws_size,
                              hipStream_t stream) {
    const float* x     = (const float*)d_in[0];
    const float* W_syn = (const float*)d_in[1];
    const float* b_syn = (const float*)d_in[2];
    const float* W_in  = (const float*)d_in[3];
    const float* b_in  = (const float*)d_in[4];
    float* out = (float*)d_out;

    const int B = in_sizes[0] / D_IN;   // 65536

    snn_main<<<dim3(B / ROWS_PER_BLOCK), dim3(THREADS), 0, stream>>>(
        x, W_syn, b_syn, W_in, b_in, out, B);
}

// Round 9
// 637.155 us; speedup vs baseline: 1.0605x; 1.0605x over previous
//
#include <hip/hip_runtime.h>

#define D_IN 64
#define D_H 128
#define L_STEPS 16
#define ROWS_PER_BLOCK 32
#define THREADS 256

typedef float f32x4 __attribute__((ext_vector_type(4)));   // native vec for nontemporal

// ---------------------------------------------------------------------------
// Kernel A — bit-exact numpy f32 GEMM chains (verified in round 6):
//   h = x @ W_syn + b_syn   (per-element sequential FMA chain, k ascending)
//   I = h @ W_in  + b_in    (same), written to workspace [B, 128] f32.
// Each block: 32 rows, 256 threads.
// ---------------------------------------------------------------------------
__global__ __launch_bounds__(THREADS) void snn_gemm(
        const float* __restrict__ x,
        const float* __restrict__ W_syn,
        const float* __restrict__ b_syn,
        const float* __restrict__ W_in,
        const float* __restrict__ b_in,
        float* __restrict__ I_out,
        int B) {
    __shared__ float xs[ROWS_PER_BLOCK][D_IN];    // 8 KB
    __shared__ float hs[ROWS_PER_BLOCK][D_H];     // 16 KB

    const int tid = threadIdx.x;
    const long long row0 = (long long)blockIdx.x * ROWS_PER_BLOCK;

    // cooperative x block load (2048 floats = 512 float4)
    {
        const float4* src = (const float4*)(x + row0 * D_IN);
        float4* dst = (float4*)&xs[0][0];
        dst[tid]       = src[tid];
        dst[tid + 256] = src[tid + 256];
    }
    __syncthreads();

    // stage 1: h[r][j], sequential FMA chain over i = 0..63
    {
        const int j = tid & 127;
        const int rbase = tid >> 7;       // 0 or 1
        float wreg[D_IN];
#pragma unroll
        for (int i = 0; i < D_IN; ++i) wreg[i] = W_syn[i * D_H + j];
        const float bs = b_syn[j];
#pragma unroll
        for (int ii = 0; ii < 16; ++ii) {
            const int r = rbase + 2 * ii;
            const float4* xr = (const float4*)&xs[r][0];
            float acc = 0.0f;
#pragma unroll
            for (int i4 = 0; i4 < 16; ++i4) {          // i ascending, one chain
                float4 xv = xr[i4];
                acc = __fmaf_rn(xv.x, wreg[4 * i4 + 0], acc);
                acc = __fmaf_rn(xv.y, wreg[4 * i4 + 1], acc);
                acc = __fmaf_rn(xv.z, wreg[4 * i4 + 2], acc);
                acc = __fmaf_rn(xv.w, wreg[4 * i4 + 3], acc);
            }
            hs[r][j] = __fadd_rn(acc, bs);             // numpy's separate +b_syn
        }
    }
    __syncthreads();

    // stage 2: I[r][n], sequential FMA chain over j = 0..127
    const int h0 = (tid & 31) * 4;
    const int rg = (tid >> 5) * 4;

    float acc[4][4];
#pragma unroll
    for (int rr = 0; rr < 4; ++rr)
#pragma unroll
        for (int q = 0; q < 4; ++q) acc[rr][q] = 0.0f;

#pragma unroll 8
    for (int j4 = 0; j4 < 32; ++j4) {
        float hrow[4][4];
#pragma unroll
        for (int rr = 0; rr < 4; ++rr) {
            float4 h4 = *(const float4*)&hs[rg + rr][4 * j4];
            hrow[rr][0] = h4.x; hrow[rr][1] = h4.y;
            hrow[rr][2] = h4.z; hrow[rr][3] = h4.w;
        }
#pragma unroll
        for (int q4 = 0; q4 < 4; ++q4) {               // j ascending
            const int j = 4 * j4 + q4;
            float4 w = *(const float4*)&W_in[j * D_H + h0];
#pragma unroll
            for (int rr = 0; rr < 4; ++rr) {
                const float hv = hrow[rr][q4];
                acc[rr][0] = __fmaf_rn(hv, w.x, acc[rr][0]);
                acc[rr][1] = __fmaf_rn(hv, w.y, acc[rr][1]);
                acc[rr][2] = __fmaf_rn(hv, w.z, acc[rr][2]);
                acc[rr][3] = __fmaf_rn(hv, w.w, acc[rr][3]);
            }
        }
    }

    const float4 bi = *(const float4*)&b_in[h0];
#pragma unroll
    for (int rr = 0; rr < 4; ++rr) {
        float4 Iv;
        Iv.x = __fadd_rn(acc[rr][0], bi.x);            // numpy's separate +b_in
        Iv.y = __fadd_rn(acc[rr][1], bi.y);
        Iv.z = __fadd_rn(acc[rr][2], bi.z);
        Iv.w = __fadd_rn(acc[rr][3], bi.w);
        *(float4*)(I_out + (size_t)(row0 + rg + rr) * D_H + (size_t)h0) = Iv;
    }
}

// ---------------------------------------------------------------------------
// Kernel B — streaming recurrence. Lean (low VGPR, max occupancy), grid-stride
// over float4 quads of I; identical uncontracted f32 arithmetic; nontemporal
// coalesced stores of 16 spike planes + v_final.
// ---------------------------------------------------------------------------
__global__ __launch_bounds__(256) void snn_recur(
        const float* __restrict__ I,
        float* __restrict__ out,
        int B) {
    const size_t BH = (size_t)B * D_H;
    const size_t nquads = BH >> 2;
    const size_t stride = (size_t)gridDim.x * 256u;
    float* __restrict__ vout = out + (size_t)L_STEPS * BH;

    for (size_t q = (size_t)blockIdx.x * 256u + threadIdx.x; q < nquads; q += stride) {
        const f32x4 I4 = ((const f32x4*)I)[q];
        const float I0 = I4.x, I1 = I4.y, I2 = I4.z, I3 = I4.w;
        float v0 = 0.f, v1 = 0.f, v2 = 0.f, v3 = 0.f;
        float s0 = 0.f, s1 = 0.f, s2 = 0.f, s3 = 0.f;
        float* base = out + 4 * q;
#pragma unroll
        for (int t = 0; t < L_STEPS; ++t) {
            v0 = __fsub_rn(__fadd_rn(__fmul_rn(0.9f, v0), I0), s0);
            v1 = __fsub_rn(__fadd_rn(__fmul_rn(0.9f, v1), I1), s1);
            v2 = __fsub_rn(__fadd_rn(__fmul_rn(0.9f, v2), I2), s2);
            v3 = __fsub_rn(__fadd_rn(__fmul_rn(0.9f, v3), I3), s3);
            s0 = (v0 >= 1.0f) ? 1.0f : 0.0f;
            s1 = (v1 >= 1.0f) ? 1.0f : 0.0f;
            s2 = (v2 >= 1.0f) ? 1.0f : 0.0f;
            s3 = (v3 >= 1.0f) ? 1.0f : 0.0f;
            f32x4 s4 = {s0, s1, s2, s3};
            __builtin_nontemporal_store(s4, (f32x4*)(base + (size_t)t * BH));
        }
        f32x4 v4 = {v0, v1, v2, v3};
        __builtin_nontemporal_store(v4, (f32x4*)(vout + 4 * q));
    }
}

extern "C" void kernel_launch(void* const* d_in, const int* in_sizes, int n_in,
                              void* d_out, int out_size, void* d_ws, size_t ws_size,
                              hipStream_t stream) {
    const float* x     = (const float*)d_in[0];
    const float* W_syn = (const float*)d_in[1];
    const float* b_syn = (const float*)d_in[2];
    const float* W_in  = (const float*)d_in[3];
    const float* b_in  = (const float*)d_in[4];
    float* out = (float*)d_out;

    const int B = in_sizes[0] / D_IN;   // 65536
    float* I = (float*)d_ws;            // B*128 f32 = 33.5 MB scratch

    snn_gemm<<<dim3(B / ROWS_PER_BLOCK), dim3(THREADS), 0, stream>>>(
        x, W_syn, b_syn, W_in, b_in, I, B);

    snn_recur<<<dim3(2048), dim3(256), 0, stream>>>(I, out, B);
}